// Round 1
// baseline (61.286 us; speedup 1.0000x reference)
//
#include <hip/hip_runtime.h>
#include <hip/hip_bf16.h>

// GEMM: C[M,N] = A[M,K] * B[K,N], M=262144, K=128, N=128, fp32 in/out,
// bf16 MFMA compute (tolerance permits), memory-bound (~268 MB traffic).

typedef __bf16 bf16x8 __attribute__((ext_vector_type(8)));
typedef float  f32x16 __attribute__((ext_vector_type(16)));

#define M_TOTAL (64 * 4096)     // 262144 rows
#define KDIM 128
#define NDIM 128
#define BM 128                  // rows per M-tile (4 waves x 32 rows)
#define NTILES (M_TOTAL / BM)   // 2048

__global__ __launch_bounds__(256) void emb_gemm_kernel(
    const float* __restrict__ A, const float* __restrict__ Emb,
    float* __restrict__ C) {
  // B fragments, bf16, pre-packed in MFMA operand order:
  // [tile = kk*4+nn][lane][reg0..7]  -> ds_read_b128 per fragment, conflict-free
  __shared__ short lds_b[32 * 64 * 8];   // 32 KiB

  const int tid = threadIdx.x;

  // ---- Stage embedding (fp32 global, L2-resident) -> bf16 B-frag layout ----
  // B[k][n] maps to: tile=(k>>4)*4+(n>>5), lane=(n&31)+32*((k>>3)&1), reg=k&7
  for (int base = tid * 4; base < KDIM * NDIM; base += 256 * 4) {
    const float4 v = *(const float4*)(Emb + base);
    const int k  = base >> 7;       // 4 | 128, so one row per float4
    const int n0 = base & 127;
    const int reg  = k & 7;
    const int toff = ((k >> 4) << 2);
    const int lhi  = ((k >> 3) & 1) << 5;
#pragma unroll
    for (int j = 0; j < 4; ++j) {
      const int n = n0 + j;
      const int tile = toff + (n >> 5);
      const int lane = (n & 31) + lhi;
      const float f = (j == 0) ? v.x : (j == 1) ? v.y : (j == 2) ? v.z : v.w;
      __bf16 h = (__bf16)f;
      lds_b[(tile * 64 + lane) * 8 + reg] = *(short*)&h;
    }
  }
  __syncthreads();

  const int lane    = tid & 63;
  const int wave    = tid >> 6;
  const int colhalf = lane >> 5;            // 0 or 1
  const bf16x8* bbase = (const bf16x8*)lds_b;

  for (int mt = blockIdx.x; mt < NTILES; mt += gridDim.x) {
    const int row0 = mt * BM + wave * 32;   // this wave's 32-row stripe
    const int arow = row0 + (lane & 31);
    const float* ap = A + (size_t)arow * KDIM + colhalf * 8;

    f32x16 acc0 = {}, acc1 = {}, acc2 = {}, acc3 = {};

#pragma unroll
    for (int kk = 0; kk < 8; ++kk) {
      // A fragment: lane holds A[row][kk*16 + colhalf*8 + (0..7)]
      const float4 a0 = *(const float4*)(ap + kk * 16);
      const float4 a1 = *(const float4*)(ap + kk * 16 + 4);
      bf16x8 af;
      af[0] = (__bf16)a0.x; af[1] = (__bf16)a0.y;
      af[2] = (__bf16)a0.z; af[3] = (__bf16)a0.w;
      af[4] = (__bf16)a1.x; af[5] = (__bf16)a1.y;
      af[6] = (__bf16)a1.z; af[7] = (__bf16)a1.w;

      const int tb = (kk * 4) * 64 + lane;
      acc0 = __builtin_amdgcn_mfma_f32_32x32x16_bf16(af, bbase[tb +   0], acc0, 0, 0, 0);
      acc1 = __builtin_amdgcn_mfma_f32_32x32x16_bf16(af, bbase[tb +  64], acc1, 0, 0, 0);
      acc2 = __builtin_amdgcn_mfma_f32_32x32x16_bf16(af, bbase[tb + 128], acc2, 0, 0, 0);
      acc3 = __builtin_amdgcn_mfma_f32_32x32x16_bf16(af, bbase[tb + 192], acc3, 0, 0, 0);
    }

    // C layout (32x32): col = lane&31, row = (reg&3) + 8*(reg>>2) + 4*colhalf
    float* c0 = C + (size_t)row0 * NDIM + (lane & 31);
#pragma unroll
    for (int reg = 0; reg < 16; ++reg) {
      const int r = (reg & 3) + ((reg >> 2) << 3) + (colhalf << 2);
      float* cr = c0 + (size_t)r * NDIM;
      cr[0]  = acc0[reg];
      cr[32] = acc1[reg];
      cr[64] = acc2[reg];
      cr[96] = acc3[reg];
    }
  }
}

extern "C" void kernel_launch(void* const* d_in, const int* in_sizes, int n_in,
                              void* d_out, int out_size, void* d_ws, size_t ws_size,
                              hipStream_t stream) {
  const float* A   = (const float*)d_in[0];   // inputs  (B,S,I) fp32
  const float* Emb = (const float*)d_in[1];   // embedding (I,E) fp32
  float* out = (float*)d_out;                 // (B,S,E) fp32

  // 1024 blocks x 2 M-tiles each: amortizes embedding staging, ~16 waves/CU
  emb_gemm_kernel<<<dim3(1024), dim3(256), 0, stream>>>(A, Emb, out);
}

// Round 2
// 56.377 us; speedup vs baseline: 1.0871x; 1.0871x over previous
//
#include <hip/hip_runtime.h>
#include <hip/hip_bf16.h>

// C[M,N] = A[M,K] * B[K,N]; M=262144, K=N=128; fp32 in/out, bf16 MFMA.
// Memory-bound: ~268 MB ideal traffic -> ~43 us floor @ 6.3 TB/s.
//
// Structure: pack_b_kernel packs the 64 KB embedding once into d_ws as bf16
// MFMA B-fragments (exact operand order); main kernel DMA-stages those 32 KB
// into LDS via global_load_lds (conflict-free, no VGPR round-trip), then each
// of 4 waves computes a 32x128 output stripe with 32 MFMAs.

typedef __bf16 bf16x8 __attribute__((ext_vector_type(8)));
typedef float  f32x16 __attribute__((ext_vector_type(16)));
typedef unsigned short ushortx8 __attribute__((ext_vector_type(8)));

#define M_TOTAL (64 * 4096)     // 262144 rows
#define KDIM 128
#define NDIM 128
#define BM 128                  // rows per block (4 waves x 32 rows)
#define NTILES (M_TOTAL / BM)   // 2048

// Fragment (tile, lane, reg) holds B[k][n] with:
//   n = (tile&3)*32 + (lane&31),  k = (tile>>2)*16 + (lane>>5)*8 + reg
// (inverse of: tile=(k>>4)*4+(n>>5), lane=(n&31)+32*((k>>3)&1), reg=k&7)
__global__ __launch_bounds__(256) void pack_b_kernel(
    const float* __restrict__ Emb, ushortx8* __restrict__ Bp) {
  const int f    = blockIdx.x * 256 + threadIdx.x;   // 0..2047
  const int tile = f >> 6;
  const int lane = f & 63;
  const int n  = ((tile & 3) << 5) + (lane & 31);
  const int k0 = ((tile >> 2) << 4) + ((lane >> 5) << 3);
  ushortx8 frag;
#pragma unroll
  for (int r = 0; r < 8; ++r) {
    __bf16 h = (__bf16)Emb[(k0 + r) * NDIM + n];
    frag[r] = *(unsigned short*)&h;
  }
  Bp[f] = frag;
}

__global__ __launch_bounds__(256) void emb_gemm_kernel(
    const float* __restrict__ A, const ushortx8* __restrict__ Bp,
    float* __restrict__ C) {
  __shared__ ushortx8 lds_b[2048];   // 32 KiB, linear fragment order

  const int tid = threadIdx.x;

  // ---- DMA-stage packed B -> LDS (linear, conflict-free, async) ----
#pragma unroll
  for (int i = 0; i < 8; ++i) {
    const int c = (i << 8) + tid;
    __builtin_amdgcn_global_load_lds(
        (const __attribute__((address_space(1))) void*)(Bp + c),
        (__attribute__((address_space(3))) void*)(&lds_b[c]),
        16, 0, 0);
  }

  const int lane    = tid & 63;
  const int wave    = tid >> 6;
  const int colhalf = lane >> 5;
  const int row0 = blockIdx.x * BM + wave * 32;
  const int arow = row0 + (lane & 31);
  const float* ap = A + (size_t)arow * KDIM + colhalf * 8;

  // Prefetch first half of A (kk=0..3) so HBM latency overlaps the stage DMA.
  float4 apre[8];
#pragma unroll
  for (int kk = 0; kk < 4; ++kk) {
    apre[kk * 2]     = *(const float4*)(ap + kk * 16);
    apre[kk * 2 + 1] = *(const float4*)(ap + kk * 16 + 4);
  }

  __syncthreads();   // drains vmcnt(0): stage DMA + A prefetch both complete

  f32x16 acc0 = {}, acc1 = {}, acc2 = {}, acc3 = {};
  const bf16x8* bbase = (const bf16x8*)lds_b;

#pragma unroll
  for (int kk = 0; kk < 8; ++kk) {
    float4 a0, a1;
    if (kk < 4) {
      a0 = apre[kk * 2];
      a1 = apre[kk * 2 + 1];
    } else {
      a0 = *(const float4*)(ap + kk * 16);
      a1 = *(const float4*)(ap + kk * 16 + 4);
    }
    bf16x8 af;
    af[0] = (__bf16)a0.x; af[1] = (__bf16)a0.y;
    af[2] = (__bf16)a0.z; af[3] = (__bf16)a0.w;
    af[4] = (__bf16)a1.x; af[5] = (__bf16)a1.y;
    af[6] = (__bf16)a1.z; af[7] = (__bf16)a1.w;

    const int tb = (kk * 4) * 64 + lane;
    acc0 = __builtin_amdgcn_mfma_f32_32x32x16_bf16(af, bbase[tb +   0], acc0, 0, 0, 0);
    acc1 = __builtin_amdgcn_mfma_f32_32x32x16_bf16(af, bbase[tb +  64], acc1, 0, 0, 0);
    acc2 = __builtin_amdgcn_mfma_f32_32x32x16_bf16(af, bbase[tb + 128], acc2, 0, 0, 0);
    acc3 = __builtin_amdgcn_mfma_f32_32x32x16_bf16(af, bbase[tb + 192], acc3, 0, 0, 0);
  }

  // C layout (32x32 MFMA): col = lane&31, row = (reg&3) + 8*(reg>>2) + 4*colhalf
  float* c0 = C + (size_t)row0 * NDIM + (lane & 31);
#pragma unroll
  for (int reg = 0; reg < 16; ++reg) {
    const int r = (reg & 3) + ((reg >> 2) << 3) + (colhalf << 2);
    float* cr = c0 + (size_t)r * NDIM;
    cr[0]  = acc0[reg];
    cr[32] = acc1[reg];
    cr[64] = acc2[reg];
    cr[96] = acc3[reg];
  }
}

extern "C" void kernel_launch(void* const* d_in, const int* in_sizes, int n_in,
                              void* d_out, int out_size, void* d_ws, size_t ws_size,
                              hipStream_t stream) {
  const float* A   = (const float*)d_in[0];   // inputs  (B,S,I) fp32
  const float* Emb = (const float*)d_in[1];   // embedding (I,E) fp32
  float* out = (float*)d_out;                 // (B,S,E) fp32
  ushortx8* Bp = (ushortx8*)d_ws;             // 32 KiB packed B fragments

  pack_b_kernel<<<dim3(8), dim3(256), 0, stream>>>(Emb, Bp);
  emb_gemm_kernel<<<dim3(NTILES), dim3(256), 0, stream>>>(A, Bp, out);
}

// Round 3
// 49.522 us; speedup vs baseline: 1.2376x; 1.1384x over previous
//
#include <hip/hip_runtime.h>
#include <hip/hip_bf16.h>

// C[M,N] = A[M,K] * B[K,N]; M=262144, K=N=128; fp32 in/out, bf16 MFMA.
// Memory-bound. Structure: pack_b_kernel packs embedding once into d_ws as
// bf16 MFMA B-fragments; main kernel: 512 threads (8 waves), DMA-stages 32 KB
// of B into LDS ONCE, one barrier, then free-runs 2 tiles of 256 rows with
// zero barriers; next-tile A prefetch overlaps store drain; C stores are
// non-temporal so they don't evict A from L2/L3.

typedef __bf16 bf16x8 __attribute__((ext_vector_type(8)));
typedef float  f32x16 __attribute__((ext_vector_type(16)));
typedef unsigned short ushortx8 __attribute__((ext_vector_type(8)));

#define M_TOTAL (64 * 4096)       // 262144 rows
#define KDIM 128
#define NDIM 128
#define TPB 512                   // 8 waves
#define BM 256                    // rows per tile (8 waves x 32 rows)
#define GRID 512                  // blocks; each does 2 tiles
#define TILES_PER_BLK 2

// Fragment (tile, lane, reg) holds B[k][n]:
//   n = (tile&3)*32 + (lane&31),  k = (tile>>2)*16 + (lane>>5)*8 + reg
__global__ __launch_bounds__(256) void pack_b_kernel(
    const float* __restrict__ Emb, ushortx8* __restrict__ Bp) {
  const int f    = blockIdx.x * 256 + threadIdx.x;   // 0..2047
  const int tile = f >> 6;
  const int lane = f & 63;
  const int n  = ((tile & 3) << 5) + (lane & 31);
  const int k0 = ((tile >> 2) << 4) + ((lane >> 5) << 3);
  ushortx8 frag;
#pragma unroll
  for (int r = 0; r < 8; ++r) {
    __bf16 h = (__bf16)Emb[(k0 + r) * NDIM + n];
    frag[r] = *(unsigned short*)&h;
  }
  Bp[f] = frag;
}

__device__ __forceinline__ bf16x8 cvt_frag(const float4 a0, const float4 a1) {
  bf16x8 af;
  af[0] = (__bf16)a0.x; af[1] = (__bf16)a0.y;
  af[2] = (__bf16)a0.z; af[3] = (__bf16)a0.w;
  af[4] = (__bf16)a1.x; af[5] = (__bf16)a1.y;
  af[6] = (__bf16)a1.z; af[7] = (__bf16)a1.w;
  return af;
}

__global__ __launch_bounds__(TPB) void emb_gemm_kernel(
    const float* __restrict__ A, const ushortx8* __restrict__ Bp,
    float* __restrict__ C) {
  __shared__ ushortx8 lds_b[2048];   // 32 KiB, linear fragment order

  const int tid = threadIdx.x;

  // ---- DMA-stage packed B -> LDS (linear, conflict-free, async) ----
#pragma unroll
  for (int i = 0; i < 4; ++i) {
    const int c = i * TPB + tid;
    __builtin_amdgcn_global_load_lds(
        (const __attribute__((address_space(1))) void*)(Bp + c),
        (__attribute__((address_space(3))) void*)(&lds_b[c]),
        16, 0, 0);
  }

  const int lane    = tid & 63;
  const int wave    = tid >> 6;            // 0..7
  const int colhalf = lane >> 5;
  const int koff    = colhalf * 8;         // k-offset within 16-wide k-step
  const bf16x8* bbase = (const bf16x8*)lds_b;

  // Prefetch tile 0 first-half A (kk=0..3) so HBM latency overlaps stage DMA.
  const int rbase = wave * 32 + (lane & 31);
  const float* ap0 = A + (size_t)(blockIdx.x * BM + rbase) * KDIM + koff;
  float4 apre[8];
#pragma unroll
  for (int kk = 0; kk < 4; ++kk) {
    apre[kk * 2]     = *(const float4*)(ap0 + kk * 16);
    apre[kk * 2 + 1] = *(const float4*)(ap0 + kk * 16 + 4);
  }

  __syncthreads();   // one barrier for the whole kernel: stage DMA complete

#pragma unroll 1
  for (int it = 0; it < TILES_PER_BLK; ++it) {
    const int mt  = blockIdx.x + it * GRID;          // tile index
    const int row0 = mt * BM + wave * 32;
    const float* ap = A + (size_t)(row0 + (lane & 31)) * KDIM + koff;

    f32x16 acc0 = {}, acc1 = {}, acc2 = {}, acc3 = {};

    // kk = 0..3 from prefetch regs
#pragma unroll
    for (int kk = 0; kk < 4; ++kk) {
      const bf16x8 af = cvt_frag(apre[kk * 2], apre[kk * 2 + 1]);
      const int tb = (kk * 4) * 64 + lane;
      acc0 = __builtin_amdgcn_mfma_f32_32x32x16_bf16(af, bbase[tb +   0], acc0, 0, 0, 0);
      acc1 = __builtin_amdgcn_mfma_f32_32x32x16_bf16(af, bbase[tb +  64], acc1, 0, 0, 0);
      acc2 = __builtin_amdgcn_mfma_f32_32x32x16_bf16(af, bbase[tb + 128], acc2, 0, 0, 0);
      acc3 = __builtin_amdgcn_mfma_f32_32x32x16_bf16(af, bbase[tb + 192], acc3, 0, 0, 0);
    }

    // kk = 4..7 loaded inline
#pragma unroll
    for (int kk = 4; kk < 8; ++kk) {
      const float4 a0 = *(const float4*)(ap + kk * 16);
      const float4 a1 = *(const float4*)(ap + kk * 16 + 4);
      const bf16x8 af = cvt_frag(a0, a1);
      const int tb = (kk * 4) * 64 + lane;
      acc0 = __builtin_amdgcn_mfma_f32_32x32x16_bf16(af, bbase[tb +   0], acc0, 0, 0, 0);
      acc1 = __builtin_amdgcn_mfma_f32_32x32x16_bf16(af, bbase[tb +  64], acc1, 0, 0, 0);
      acc2 = __builtin_amdgcn_mfma_f32_32x32x16_bf16(af, bbase[tb + 128], acc2, 0, 0, 0);
      acc3 = __builtin_amdgcn_mfma_f32_32x32x16_bf16(af, bbase[tb + 192], acc3, 0, 0, 0);
    }

    // Issue NEXT tile's first-half A loads now, so they overlap the store
    // drain below (apre is dead after kk=3's MFMAs).
    if (it + 1 < TILES_PER_BLK) {
      const float* apn = A + (size_t)((mt + GRID) * BM + rbase) * KDIM + koff;
#pragma unroll
      for (int kk = 0; kk < 4; ++kk) {
        apre[kk * 2]     = *(const float4*)(apn + kk * 16);
        apre[kk * 2 + 1] = *(const float4*)(apn + kk * 16 + 4);
      }
    }

    // C layout (32x32 MFMA): col = lane&31, row = (reg&3)+8*(reg>>2)+4*colhalf
    float* c0 = C + (size_t)row0 * NDIM + (lane & 31);
#pragma unroll
    for (int reg = 0; reg < 16; ++reg) {
      const int r = (reg & 3) + ((reg >> 2) << 3) + (colhalf << 2);
      float* cr = c0 + (size_t)r * NDIM;
      __builtin_nontemporal_store(acc0[reg], cr + 0);
      __builtin_nontemporal_store(acc1[reg], cr + 32);
      __builtin_nontemporal_store(acc2[reg], cr + 64);
      __builtin_nontemporal_store(acc3[reg], cr + 96);
    }
  }
}

extern "C" void kernel_launch(void* const* d_in, const int* in_sizes, int n_in,
                              void* d_out, int out_size, void* d_ws, size_t ws_size,
                              hipStream_t stream) {
  const float* A   = (const float*)d_in[0];   // inputs  (B,S,I) fp32
  const float* Emb = (const float*)d_in[1];   // embedding (I,E) fp32
  float* out = (float*)d_out;                 // (B,S,E) fp32
  ushortx8* Bp = (ushortx8*)d_ws;             // 32 KiB packed B fragments

  pack_b_kernel<<<dim3(8), dim3(256), 0, stream>>>(Emb, Bp);
  emb_gemm_kernel<<<dim3(GRID), dim3(TPB), 0, stream>>>(A, Bp, out);
}